// Round 2
// baseline (408.509 us; speedup 1.0000x reference)
//
#include <hip/hip_runtime.h>
#include <cstddef>

#define B 2048
#define T 128
#define S 16
#define NL 128
#define IN 32
#define OUT 8
#define DT 0.01f

// 8 fixed-point iterations per t, two timesteps software-pipelined with a
// 5-round stagger (iters 1-4 of t on extrapolated cstx(2x_{t-1}-x_{t-2}),
// iters 5-8 exact).  NEW in this round: only 4 compute waves, each owning TWO
// 16-col tiles of NL.  The MFMA B-operand (w^T fragments) is identical for
// every tile, so a 2-tile wave still issues only 4 ds_read_b128 per iteration
// -> LDS read traffic in the w-loop drops 4x vs the 8-wave version (the
// measured round-latency wall: 64 reads x ~12cy = 768cy/round of LDS pipe).
// Waves 4-5 run the epilogue (parallel with iter4), waves 6-7 stage y.

#define NBLK_R (B / 16)          // 128 rinn blocks, 16 batch rows each
#define NBLK_V ((B * T) / 512)   // 512 value blocks, 1 sample/thread
#define NTHR 512

typedef unsigned int uint;
typedef _Float16 f16;
typedef f16 f16x8 __attribute__((ext_vector_type(8)));
typedef __fp16 fp16x2_n __attribute__((ext_vector_type(2)));  // native cvt_pkrtz type
typedef float f32x4 __attribute__((ext_vector_type(4)));

union ABu { f16x8 v; f16 h[8]; };

#define MFMA16(A, Bv, C) __builtin_amdgcn_mfma_f32_16x16x32_f16((A), (Bv), (C), 0, 0, 0)

__device__ __forceinline__ uint pkrtz_u(float a, float b) {
    fp16x2_n p = __builtin_amdgcn_cvt_pkrtz(a, b);
    return __builtin_bit_cast(uint, p);
}

// value branch tanh (has slack, keep safe clamp)
__device__ __forceinline__ float fast_tanh(float x) {
    float e = __expf(fminf(x, 10.f) * 2.f);
    return fmaf(-2.f, __builtin_amdgcn_rcpf(e + 1.f), 1.f);
}

// paired tanh -> packed half2, one shared v_rcp
__device__ __forceinline__ uint tanh2_pk(float a, float b) {
    float ea = __expf(a * 2.f);
    float eb = __expf(b * 2.f);
    float da = ea + 1.f, db = eb + 1.f;
    float r  = __builtin_amdgcn_rcpf(da * db);
    float ta = fmaf(-2.f, db * r, 1.f);
    float tb = fmaf(-2.f, da * r, 1.f);
    return pkrtz_u(ta, tb);
}

// LDS chunk layout for a 16(m) x K(k) fp16 matrix: chunk (cc=k>>3, m) holds 8
// consecutive k of row m at byte ((cc*16+m)*16 + (k&7)*2).  B-fragment read for
// MFMA k-step s (quad q, lane m=l15): one ds_read_b128 at ((s*4+q)*16+m)*16.

struct __align__(16) RinnS {
    char wbufs[2][2][4096];  // per-slot (t&1) w ping-pong buffers (16 x 128 fp16)
    char xbuf[2][1024];      // x_t (f16, K=32 with k>=16 zero pad), per t parity
    char ybuf[3][1024];      // y_t (f16, K=32), ring of 3
    float xs[16][16];        // fp32 master copy of state
};
struct __align__(16) ValueS {
    float W0[IN][64];
    float W1[64][64];
    float W2v[64], b0v[64], b1v[64];
    float b2v;
    float lsv[OUT];
};
union SmU { RinnS r; ValueS v; };

#define LOAD_W(rb, A0, A1, A2, A3) do { const char* _p = (rb);                 \
    A0 = *(const f16x8*)(_p + rd_off);        A1 = *(const f16x8*)(_p + rd_off + 1024); \
    A2 = *(const f16x8*)(_p + rd_off + 2048); A3 = *(const f16x8*)(_p + rd_off + 3072); } while (0)

// dual-tile iteration body for one chain; shared B-operand reads A0..A3
#define ITER2(CSTARR, A0, A1, A2, A3, WDST) do {                               \
    _Pragma("unroll")                                                          \
    for (int _ti = 0; _ti < 2; ++_ti) {                                        \
        f32x4 _p0 = (CSTARR)[_ti], _p1 = zero4;                                \
        _p0 = MFMA16(D[_ti][0].v, A0, _p0); _p1 = MFMA16(D[_ti][1].v, A1, _p1);\
        _p0 = MFMA16(D[_ti][2].v, A2, _p0); _p1 = MFMA16(D[_ti][3].v, A3, _p1);\
        f32x4 _z = _p0 + _p1;                                                  \
        uint2 _w; _w.x = tanh2_pk(_z.x, _z.y); _w.y = tanh2_pk(_z.z, _z.w);    \
        *(uint2*)((WDST) + wa2[_ti]) = _w;                                     \
    } } while (0)

__global__ void __launch_bounds__(NTHR, 1)
fused_kernel(const float* __restrict__ obs, const float* __restrict__ x0,
             const float* __restrict__ A_T, const float* __restrict__ Bw_T,
             const float* __restrict__ By_T, const float* __restrict__ Cv_T,
             const float* __restrict__ Dvw_T, const float* __restrict__ Dvy_T,
             const float* __restrict__ Cu_T, const float* __restrict__ Duw_T,
             const float* __restrict__ Duy_T, const float* __restrict__ log_stds,
             const float* __restrict__ W0, const float* __restrict__ b0,
             const float* __restrict__ W1, const float* __restrict__ b1,
             const float* __restrict__ W2, const float* __restrict__ b2,
             float* __restrict__ out) {
    __shared__ SmU sm;
    const int tid = threadIdx.x;

    if (blockIdx.x < NBLK_R) {
        // ======================= recurrent branch =======================
        RinnS& R = sm.r;
        const int wave = tid >> 6, lane = tid & 63;
        const int q = lane >> 4, l15 = lane & 15;
        const int b0r = blockIdx.x * 16;
        const bool cw = (wave < 4);          // compute waves: 2 col-tiles each
        const bool ew = (wave == 4 || wave == 5);  // epilogue waves

        // ---- iteration-invariant A-operand fragments (fp16) ----
        ABu D[2][4];   // Dvw^T blocks, per tile per k-step
        ABu Cx[2], Cy[2];
        int wa2[2];
        if (cw) {
#pragma unroll
            for (int ti = 0; ti < 2; ++ti) {
                const int ct = wave * 32 + ti * 16;
#pragma unroll
                for (int s2 = 0; s2 < 4; ++s2)
#pragma unroll
                    for (int j = 0; j < 8; ++j) {
                        int k = 32 * s2 + 8 * q + j;
                        D[ti][s2].h[j] = (f16)Dvw_T[k * NL + ct + l15];
                    }
#pragma unroll
                for (int j = 0; j < 8; ++j) {
                    int k = 8 * q + j;
                    Cx[ti].h[j] = (f16)((k < 16) ? Cv_T[k * NL + ct + l15] : 0.f);
                    Cy[ti].h[j] = (f16)Dvy_T[k * NL + ct + l15];
                }
                wa2[ti] = (((ct >> 3) + (q >> 1)) * 16 + l15) * 16 + (q & 1) * 8;
            }
        }
        // epilogue: [u|xn]^T = W^T (A) * [x(32)|y(32)|w(128)]^T (B), K=192
        ABu EPf[6];
        if (ew) {
            int oc = (wave - 4) * 16 + l15;  // 0..7=u, 8..23=xnext, >=24 pad
#pragma unroll
            for (int s2 = 0; s2 < 6; ++s2)
#pragma unroll
                for (int j = 0; j < 8; ++j) {
                    int k = 32 * s2 + 8 * q + j;
                    float v = 0.f;
                    if (oc < 24) {
                        if (k < 16)       v = (oc < 8) ? Cu_T[k * OUT + oc] : A_T[k * S + (oc - 8)];
                        else if (k >= 32 && k < 64) { int ky = k - 32;
                                          v = (oc < 8) ? Duy_T[ky * OUT + oc] : By_T[ky * S + (oc - 8)]; }
                        else if (k >= 64) { int kw = k - 64;
                                          v = (oc < 8) ? Duw_T[kw * OUT + oc] : Bw_T[kw * S + (oc - 8)]; }
                    }
                    EPf[s2].h[j] = (f16)v;
                }
        }

        // ---- init staging: xs, xbuf[0]=xbuf[1]=x0 (+zero pads), ybuf[0/1]=y0/y1
        if (tid < 256) { int m = tid >> 4, c = tid & 15; R.xs[m][c] = x0[(b0r + m) * S + c]; }
        if (tid < 128) {
            int m = tid >> 3, pr = tid & 7, k = 2 * pr;
            uint u = pkrtz_u(x0[(b0r + m) * S + k], x0[(b0r + m) * S + k + 1]);
            uint off = ((k >> 3) * 16 + m) * 16 + (k & 7) * 2;
            *(uint*)(R.xbuf[0] + off) = u;
            *(uint*)(R.xbuf[1] + off) = u;
        } else if (tid < 384) {   // zero pads: bytes 512..1023 of both xbufs
            int i = tid - 128, buf = i >> 7, d = i & 127;
            *(uint*)(R.xbuf[buf] + 512 + d * 4) = 0u;
        }
        {   // ybuf[0] <- y(0), ybuf[1] <- y(1): 512 pair-slots, one per thread
            int buf = tid >> 8, ii = tid & 255, m = ii >> 4, pr = ii & 15, k = 2 * pr;
            const float* yp = obs + ((size_t)(b0r + m) * T + buf) * IN + k;
            *(uint*)(R.ybuf[buf] + ((k >> 3) * 16 + m) * 16 + (k & 7) * 2) =
                pkrtz_u(yp[0], yp[1]);
        }

        const int rd_off = (q * 16 + l15) * 16;  // + s*1024
        __syncthreads();

        f32x4 cst_cur[2], cst_prv[2], csty[2], hx1[2], hx2[2];
        const f32x4 zero4 = {0.f, 0.f, 0.f, 0.f};
#pragma unroll
        for (int ti = 0; ti < 2; ++ti) {
            cst_cur[ti] = zero4; cst_prv[ti] = zero4; csty[ti] = zero4;
            hx1[ti] = zero4; hx2[ti] = zero4;
        }

        for (int t = 0; t <= T; ++t) {
            const int s = t & 1;
            const bool hc = (t < T);   // current-slot work exists
            const bool hp = (t > 0);   // previous-slot work exists

            // ---------- j=0: u0(t) [cst extrapolate + iter1] || iter6(t-1)
            {
                f16x8 yb, a0, a1, a2, a3;
                if (cw && hc) yb = *(const f16x8*)(R.ybuf[t % 3] + rd_off);
                if (cw && hp) LOAD_W(R.wbufs[s ^ 1][1], a0, a1, a2, a3);
                if (cw && hc) {
                    if (t == 0) {
                        f16x8 xb = *(const f16x8*)(R.xbuf[1] + rd_off);
#pragma unroll
                        for (int ti = 0; ti < 2; ++ti) {
                            csty[ti] = MFMA16(Cy[ti].v, yb, zero4);
                            f32x4 cx = MFMA16(Cx[ti].v, xb, zero4);
                            hx1[ti] = cx; hx2[ti] = cx;
                            cst_cur[ti] = cx + csty[ti];
                        }
                    } else {
#pragma unroll
                        for (int ti = 0; ti < 2; ++ti) {
                            csty[ti] = MFMA16(Cy[ti].v, yb, zero4);
                            cst_cur[ti] = hx1[ti] + hx1[ti] - hx2[ti] + csty[ti];
                        }
                    }
#pragma unroll
                    for (int ti = 0; ti < 2; ++ti) {
                        uint2 w0p;
                        w0p.x = tanh2_pk(cst_cur[ti].x, cst_cur[ti].y);
                        w0p.y = tanh2_pk(cst_cur[ti].z, cst_cur[ti].w);
                        *(uint2*)(R.wbufs[s][1] + wa2[ti]) = w0p;
                    }
                }
                if (cw && hp) ITER2(cst_prv, a0, a1, a2, a3, R.wbufs[s ^ 1][0]);
                __syncthreads();
            }
            // ---------- j=1: iter2(t) || iter7(t-1)
            {
                if (cw) {
                    f16x8 c0, c1, c2, c3, p0, p1, p2, p3;
                    if (hc) LOAD_W(R.wbufs[s][1], c0, c1, c2, c3);
                    if (hp) LOAD_W(R.wbufs[s ^ 1][0], p0, p1, p2, p3);
                    if (hc) ITER2(cst_cur, c0, c1, c2, c3, R.wbufs[s][0]);
                    if (hp) ITER2(cst_prv, p0, p1, p2, p3, R.wbufs[s ^ 1][1]);
                }
                __syncthreads();
            }
            // ---------- j=2: iter3(t) || iter8(t-1)
            {
                if (cw) {
                    f16x8 c0, c1, c2, c3, p0, p1, p2, p3;
                    if (hc) LOAD_W(R.wbufs[s][0], c0, c1, c2, c3);
                    if (hp) LOAD_W(R.wbufs[s ^ 1][1], p0, p1, p2, p3);
                    if (hc) ITER2(cst_cur, c0, c1, c2, c3, R.wbufs[s][1]);
                    if (hp) ITER2(cst_prv, p0, p1, p2, p3, R.wbufs[s ^ 1][0]);
                }
                __syncthreads();
            }
            // ---------- j=3: iter4(t) (waves 0-3) || EPILOGUE(t-1) (waves 4-5)
            {
                if (cw && hc) {
                    f16x8 c0, c1, c2, c3;
                    LOAD_W(R.wbufs[s][1], c0, c1, c2, c3);
                    ITER2(cst_cur, c0, c1, c2, c3, R.wbufs[s][0]);
                }
                if (ew && hp) {
                    f16x8 xbp = *(const f16x8*)(R.xbuf[s ^ 1] + rd_off);
                    f16x8 ybp = *(const f16x8*)(R.ybuf[(t - 1) % 3] + rd_off);
                    f16x8 w0f, w1f, w2f, w3f;
                    LOAD_W(R.wbufs[s ^ 1][0], w0f, w1f, w2f, w3f);
                    f32x4 ea = MFMA16(EPf[0].v, xbp, zero4);
                    f32x4 eb = MFMA16(EPf[1].v, ybp, zero4);
                    ea = MFMA16(EPf[2].v, w0f, ea); eb = MFMA16(EPf[3].v, w1f, eb);
                    ea = MFMA16(EPf[4].v, w2f, ea); eb = MFMA16(EPf[5].v, w3f, eb);
                    f32x4 ez = ea + eb;
                    const int m = l15, tp = t - 1;
                    if (wave == 4 && q < 2) {
                        // rows 0..7: u -> global
                        const size_t o = ((size_t)(b0r + m) * T + tp) * (2 * OUT + 1);
                        out[o + 4 * q + 0] = ez.x; out[o + 4 * q + 1] = ez.y;
                        out[o + 4 * q + 2] = ez.z; out[o + 4 * q + 3] = ez.w;
                    } else if (wave == 4 || q < 2) {
                        // x_next cols: wave4 q2,q3 -> 0..7 ; wave5 q0,q1 -> 8..15
                        const int cb = (wave == 4) ? (4 * q - 8) : (8 + 4 * q);
                        float4 xv = *(const float4*)&R.xs[m][cb];
                        float4 xn;
                        xn.x = fmaf(DT, ez.x, xv.x); xn.y = fmaf(DT, ez.y, xv.y);
                        xn.z = fmaf(DT, ez.z, xv.z); xn.w = fmaf(DT, ez.w, xv.w);
                        *(float4*)&R.xs[m][cb] = xn;
                        // restage x_t (fp16) into xbuf[s] for u4(t) next round
                        uint2 pk;
                        pk.x = pkrtz_u(xn.x, xn.y); pk.y = pkrtz_u(xn.z, xn.w);
                        *(uint2*)(R.xbuf[s] + ((cb >> 3) * 16 + m) * 16 + (cb & 7) * 2) = pk;
                    }
                }
                __syncthreads();
            }
            // ---------- j=4: u4(t) [exact cst + iter5] (waves 0-3) + stage y(t+2) (waves 6-7)
            if (hc) {
                if (cw) {
                    f16x8 xb = *(const f16x8*)(R.xbuf[s] + rd_off);
                    f16x8 a0, a1, a2, a3;
                    LOAD_W(R.wbufs[s][0], a0, a1, a2, a3);
#pragma unroll
                    for (int ti = 0; ti < 2; ++ti) {
                        f32x4 pc = MFMA16(Cx[ti].v, xb, csty[ti]);  // exact cst
                        f32x4 p0 = MFMA16(D[ti][0].v, a0, zero4);
                        f32x4 p1 = MFMA16(D[ti][1].v, a1, zero4);
                        p0 = MFMA16(D[ti][2].v, a2, p0);
                        p1 = MFMA16(D[ti][3].v, a3, p1);
                        f32x4 z = pc + p0 + p1;
                        uint2 w5p;
                        w5p.x = tanh2_pk(z.x, z.y); w5p.y = tanh2_pk(z.z, z.w);
                        *(uint2*)(R.wbufs[s][1] + wa2[ti]) = w5p;
                        hx2[ti] = hx1[ti]; hx1[ti] = pc - csty[ti];
                        cst_cur[ti] = pc;
                    }
                }
                if (wave >= 6) {   // stage y(t+2) into the ring slot freed at j=3
                    int ii = tid - 384;
                    int tt = (t + 2 < T) ? (t + 2) : (T - 1);
#pragma unroll
                    for (int rep = 0; rep < 2; ++rep) {
                        int slot = ii + rep * 128;
                        int m2 = slot >> 4, pr = slot & 15, k = 2 * pr;
                        const float* yp = obs + ((size_t)(b0r + m2) * T + tt) * IN + k;
                        *(uint*)(R.ybuf[(t + 2) % 3] + ((k >> 3) * 16 + m2) * 16 + (k & 7) * 2) =
                            pkrtz_u(yp[0], yp[1]);
                    }
                }
                __syncthreads();
            }
#pragma unroll
            for (int ti = 0; ti < 2; ++ti) cst_prv[ti] = cst_cur[ti];
        }
    } else {
        // ======================= value branch (+ log_stds writes) ==========
        ValueS& V = sm.v;
        for (int i = tid; i < IN * 64; i += NTHR) ((float*)V.W0)[i] = W0[i];
        for (int i = tid; i < 64 * 64; i += NTHR) ((float*)V.W1)[i] = W1[i];
        if (tid < 64) { V.W2v[tid] = W2[tid]; V.b0v[tid] = b0[tid]; V.b1v[tid] = b1[tid]; }
        if (tid == 64) V.b2v = b2[0];
        if (tid >= 128 && tid < 128 + OUT) V.lsv[tid - 128] = log_stds[tid - 128];
        __syncthreads();

        const size_t s = (size_t)(blockIdx.x - NBLK_R) * NTHR + tid;
        float o[IN];
#pragma unroll
        for (int qq = 0; qq < IN / 4; ++qq) {
            float4 v = ((const float4*)(obs + s * IN))[qq];
            o[4 * qq] = v.x; o[4 * qq + 1] = v.y; o[4 * qq + 2] = v.z; o[4 * qq + 3] = v.w;
        }
        float h[64];
#pragma unroll
        for (int jg = 0; jg < 16; ++jg) {
            float4 a = *(const float4*)&V.b0v[4 * jg];
#pragma unroll
            for (int i = 0; i < IN; ++i) {
                float4 wr = *(const float4*)&V.W0[i][4 * jg];
                a.x = fmaf(o[i], wr.x, a.x); a.y = fmaf(o[i], wr.y, a.y);
                a.z = fmaf(o[i], wr.z, a.z); a.w = fmaf(o[i], wr.w, a.w);
            }
            h[4 * jg]     = fast_tanh(a.x); h[4 * jg + 1] = fast_tanh(a.y);
            h[4 * jg + 2] = fast_tanh(a.z); h[4 * jg + 3] = fast_tanh(a.w);
        }
        float value = V.b2v;
#pragma unroll
        for (int jg = 0; jg < 16; ++jg) {
            float4 a = *(const float4*)&V.b1v[4 * jg];
#pragma unroll
            for (int i = 0; i < 64; ++i) {
                float4 wr = *(const float4*)&V.W1[i][4 * jg];
                a.x = fmaf(h[i], wr.x, a.x); a.y = fmaf(h[i], wr.y, a.y);
                a.z = fmaf(h[i], wr.z, a.z); a.w = fmaf(h[i], wr.w, a.w);
            }
            float4 w2 = *(const float4*)&V.W2v[4 * jg];
            value = fmaf(fast_tanh(a.x), w2.x, value);
            value = fmaf(fast_tanh(a.y), w2.y, value);
            value = fmaf(fast_tanh(a.z), w2.z, value);
            value = fmaf(fast_tanh(a.w), w2.w, value);
        }
        const size_t ob = s * (2 * OUT + 1);
#pragma unroll
        for (int i = 0; i < OUT; ++i) out[ob + OUT + i] = V.lsv[i];
        out[ob + 2 * OUT] = value;
    }
}

extern "C" void kernel_launch(void* const* d_in, const int* in_sizes, int n_in,
                              void* d_out, int out_size, void* d_ws, size_t ws_size,
                              hipStream_t stream) {
    const float* obs      = (const float*)d_in[0];
    const float* x0       = (const float*)d_in[1];
    const float* A_T      = (const float*)d_in[2];
    const float* Bw_T     = (const float*)d_in[3];
    const float* By_T     = (const float*)d_in[4];
    const float* Cv_T     = (const float*)d_in[5];
    const float* Dvw_T    = (const float*)d_in[6];
    const float* Dvy_T    = (const float*)d_in[7];
    const float* Cu_T     = (const float*)d_in[8];
    const float* Duw_T    = (const float*)d_in[9];
    const float* Duy_T    = (const float*)d_in[10];
    const float* log_stds = (const float*)d_in[11];
    const float* W0       = (const float*)d_in[12];
    const float* b0       = (const float*)d_in[13];
    const float* W1       = (const float*)d_in[14];
    const float* b1       = (const float*)d_in[15];
    const float* W2       = (const float*)d_in[16];
    const float* b2       = (const float*)d_in[17];
    float* out = (float*)d_out;

    fused_kernel<<<NBLK_R + NBLK_V, NTHR, 0, stream>>>(
        obs, x0, A_T, Bw_T, By_T, Cv_T, Dvw_T, Dvy_T, Cu_T, Duw_T, Duy_T,
        log_stds, W0, b0, W1, b1, W2, b2, out);
}

// Round 3
// 394.977 us; speedup vs baseline: 1.0343x; 1.0343x over previous
//
#include <hip/hip_runtime.h>
#include <cstddef>

#define B 2048
#define T 128
#define S 16
#define NL 128
#define IN 32
#define OUT 8
#define DT 0.01f

// Rinn branch: 8 fixed-point iterations per t, two timesteps software-pipelined
// with a 5-round stagger (iters 1-4 of t on extrapolated cstx(2x_{t-1}-x_{t-2}),
// iters 5-8 exact) -- identical to the 326us round-1 version.
// NEW this round: the value branch is rewritten as an fp16 MFMA GEMM.  The old
// version issued 12288 wave-uniform ds_read_b128 per block (weights re-read
// from LDS once per 4 scalar FMAs) -- ~100k cycles of LDS-pipe occupancy per
// block, 512 blocks co-resident with the rinn blocks.  LDS is a per-CU pipe,
// so every rinn phase queued behind that flood (the schedule-invariant ~340us
// across three different rinn schedules).  Now: weights live in registers as
// A-fragments, obs -> B-fragments straight from global, inter-layer layout
// bounce via 2KB wave-private LDS scratch (no barriers), W2 dot via shuffles.

#define NBLK_R (B / 16)          // 128 rinn blocks, 16 batch rows each
#define NBLK_V ((B * T) / 512)   // 512 value blocks, 512 samples each
#define NTHR 512

typedef unsigned int uint;
typedef _Float16 f16;
typedef f16 f16x8 __attribute__((ext_vector_type(8)));
typedef __fp16 fp16x2_n __attribute__((ext_vector_type(2)));  // native cvt_pkrtz type
typedef float f32x4 __attribute__((ext_vector_type(4)));

union ABu { f16x8 v; f16 h[8]; };

#define MFMA16(A, Bv, C) __builtin_amdgcn_mfma_f32_16x16x32_f16((A), (Bv), (C), 0, 0, 0)

__device__ __forceinline__ uint pkrtz_u(float a, float b) {
    fp16x2_n p = __builtin_amdgcn_cvt_pkrtz(a, b);
    return __builtin_bit_cast(uint, p);
}

// value branch tanh (has slack, keep safe clamp)
__device__ __forceinline__ float fast_tanh(float x) {
    float e = __expf(fminf(x, 10.f) * 2.f);
    return fmaf(-2.f, __builtin_amdgcn_rcpf(e + 1.f), 1.f);
}

// paired tanh -> packed half2, one shared v_rcp
__device__ __forceinline__ uint tanh2_pk(float a, float b) {
    float ea = __expf(a * 2.f);
    float eb = __expf(b * 2.f);
    float da = ea + 1.f, db = eb + 1.f;
    float r  = __builtin_amdgcn_rcpf(da * db);
    float ta = fmaf(-2.f, db * r, 1.f);
    float tb = fmaf(-2.f, da * r, 1.f);
    return pkrtz_u(ta, tb);
}

// LDS chunk layout for a 16(m) x K(k) fp16 matrix: chunk (cc=k>>3, m) holds 8
// consecutive k of row m at byte ((cc*16+m)*16 + (k&7)*2).  B-fragment read for
// MFMA k-step s (quad q, lane m=l15): one ds_read_b128 at ((s*4+q)*16+m)*16.

struct __align__(16) RinnS {
    char wbufs[2][2][4096];  // per-slot (t&1) w ping-pong buffers (16 x 128 fp16)
    char xbuf[2][1024];      // x_t (f16, K=32 with k>=16 zero pad), per t parity
    char ybuf[3][1024];      // y_t (f16, K=32), ring of 3
    float xs[16][16];        // fp32 master copy of state
};
struct __align__(16) ValueS {
    char scr[8][2048];       // per-wave h^T bounce scratch (64k x 16m fp16)
};
union SmU { RinnS r; ValueS v; };

#define LOAD_W(rb, A0, A1, A2, A3) do { const char* _p = (rb);                 \
    A0 = *(const f16x8*)(_p + rd_off);        A1 = *(const f16x8*)(_p + rd_off + 1024); \
    A2 = *(const f16x8*)(_p + rd_off + 2048); A3 = *(const f16x8*)(_p + rd_off + 3072); } while (0)

#define ITER_BODY(CST, A0, A1, A2, A3, WDST) do {                              \
    f32x4 _p0 = (CST), _p1 = {0.f, 0.f, 0.f, 0.f};                             \
    _p0 = MFMA16(D[0].v, A0, _p0); _p1 = MFMA16(D[1].v, A1, _p1);              \
    _p0 = MFMA16(D[2].v, A2, _p0); _p1 = MFMA16(D[3].v, A3, _p1);              \
    f32x4 _z = _p0 + _p1;                                                      \
    uint2 _w; _w.x = tanh2_pk(_z.x, _z.y); _w.y = tanh2_pk(_z.z, _z.w);        \
    *(uint2*)((WDST) + wa) = _w; } while (0)

__global__ void __launch_bounds__(NTHR, 1)
fused_kernel(const float* __restrict__ obs, const float* __restrict__ x0,
             const float* __restrict__ A_T, const float* __restrict__ Bw_T,
             const float* __restrict__ By_T, const float* __restrict__ Cv_T,
             const float* __restrict__ Dvw_T, const float* __restrict__ Dvy_T,
             const float* __restrict__ Cu_T, const float* __restrict__ Duw_T,
             const float* __restrict__ Duy_T, const float* __restrict__ log_stds,
             const float* __restrict__ W0, const float* __restrict__ b0,
             const float* __restrict__ W1, const float* __restrict__ b1,
             const float* __restrict__ W2, const float* __restrict__ b2,
             float* __restrict__ out) {
    __shared__ SmU sm;
    const int tid = threadIdx.x;
    const int wave = tid >> 6, lane = tid & 63;
    const int q = lane >> 4, l15 = lane & 15;
    const int rd_off = (q * 16 + l15) * 16;  // + s*1024

    if (blockIdx.x < NBLK_R) {
        // ======================= recurrent branch =======================
        RinnS& R = sm.r;
        const int b0r = blockIdx.x * 16;
        const int ct = wave * 16;   // this wave's single 16-col tile of NL

        // ---- iteration-invariant A-operand fragments (fp16) ----
        // Z^T = Dvw^T (A) * w^T (B);  A[c_local][k]: c=ct+l15, k=32s+8q+j
        ABu D[4];
#pragma unroll
        for (int s2 = 0; s2 < 4; ++s2)
#pragma unroll
            for (int j = 0; j < 8; ++j) {
                int k = 32 * s2 + 8 * q + j;
                D[s2].h[j] = (f16)Dvw_T[k * NL + ct + l15];
            }
        // cstx^T = Cv^T (A, K=32 padded) * x^T ; csty^T = Dvy^T (A, K=32) * y^T
        ABu Cx, Cy;
#pragma unroll
        for (int j = 0; j < 8; ++j) {
            int k = 8 * q + j;
            Cx.h[j] = (f16)((k < 16) ? Cv_T[k * NL + ct + l15] : 0.f);
            Cy.h[j] = (f16)Dvy_T[k * NL + ct + l15];
        }
        // epilogue: [u|xn]^T = W^T (A) * [x(32)|y(32)|w(128)]^T (B), K=192
        ABu EPf[6];
        if (wave < 2) {
            int oc = wave * 16 + l15;  // 0..7=u, 8..23=xnext, >=24 pad
#pragma unroll
            for (int s2 = 0; s2 < 6; ++s2)
#pragma unroll
                for (int j = 0; j < 8; ++j) {
                    int k = 32 * s2 + 8 * q + j;
                    float v = 0.f;
                    if (oc < 24) {
                        if (k < 16)       v = (oc < 8) ? Cu_T[k * OUT + oc] : A_T[k * S + (oc - 8)];
                        else if (k >= 32 && k < 64) { int ky = k - 32;
                                          v = (oc < 8) ? Duy_T[ky * OUT + oc] : By_T[ky * S + (oc - 8)]; }
                        else if (k >= 64) { int kw = k - 64;
                                          v = (oc < 8) ? Duw_T[kw * OUT + oc] : Bw_T[kw * S + (oc - 8)]; }
                    }
                    EPf[s2].h[j] = (f16)v;
                }
        }

        // ---- init staging: xs, xbuf[0]=xbuf[1]=x0 (+zero pads), ybuf[0/1]=y0/y1
        if (tid < 256) { int m = tid >> 4, c = tid & 15; R.xs[m][c] = x0[(b0r + m) * S + c]; }
        if (tid < 128) {
            int m = tid >> 3, pr = tid & 7, k = 2 * pr;
            uint u = pkrtz_u(x0[(b0r + m) * S + k], x0[(b0r + m) * S + k + 1]);
            uint off = ((k >> 3) * 16 + m) * 16 + (k & 7) * 2;
            *(uint*)(R.xbuf[0] + off) = u;
            *(uint*)(R.xbuf[1] + off) = u;
        } else if (tid < 384) {   // zero pads: bytes 512..1023 of both xbufs
            int i = tid - 128, buf = i >> 7, d = i & 127;
            *(uint*)(R.xbuf[buf] + 512 + d * 4) = 0u;
        }
        {   // ybuf[0] <- y(0), ybuf[1] <- y(1): 512 pair-slots, one per thread
            int buf = tid >> 8, ii = tid & 255, m = ii >> 4, pr = ii & 15, k = 2 * pr;
            const float* yp = obs + ((size_t)(b0r + m) * T + buf) * IN + k;
            *(uint*)(R.ybuf[buf] + ((k >> 3) * 16 + m) * 16 + (k & 7) * 2) =
                pkrtz_u(yp[0], yp[1]);
        }

        const int wa = (((ct >> 3) + (q >> 1)) * 16 + l15) * 16 + (q & 1) * 8;
        __syncthreads();

        f32x4 cst_cur = {0.f, 0.f, 0.f, 0.f}, cst_prv = {0.f, 0.f, 0.f, 0.f};
        f32x4 csty    = {0.f, 0.f, 0.f, 0.f};
        f32x4 hx1     = {0.f, 0.f, 0.f, 0.f}, hx2 = {0.f, 0.f, 0.f, 0.f};
        const f32x4 zero4 = {0.f, 0.f, 0.f, 0.f};

        for (int t = 0; t <= T; ++t) {
            const int s = t & 1;
            const bool hc = (t < T);   // current-slot work exists
            const bool hp = (t > 0);   // previous-slot work exists

            // ---------- j=0: u0(t) [cst extrapolate + iter1] || iter6(t-1)
            {
                f16x8 yb, a0, a1, a2, a3;
                if (hc) yb = *(const f16x8*)(R.ybuf[t % 3] + rd_off);
                if (hp) LOAD_W(R.wbufs[s ^ 1][1], a0, a1, a2, a3);
                if (hc) {
                    csty = MFMA16(Cy.v, yb, zero4);
                    if (t == 0) {
                        f16x8 xb = *(const f16x8*)(R.xbuf[1] + rd_off);
                        f32x4 cx = MFMA16(Cx.v, xb, zero4);
                        hx1 = cx; hx2 = cx;
                        cst_cur = cx + csty;
                    } else {
                        cst_cur = hx1 + hx1 - hx2 + csty;
                    }
                    uint2 w0p;
                    w0p.x = tanh2_pk(cst_cur.x, cst_cur.y);
                    w0p.y = tanh2_pk(cst_cur.z, cst_cur.w);
                    *(uint2*)(R.wbufs[s][1] + wa) = w0p;
                }
                if (hp) ITER_BODY(cst_prv, a0, a1, a2, a3, R.wbufs[s ^ 1][0]);
                __syncthreads();
            }
            // ---------- j=1: iter2(t) || iter7(t-1)
            {
                f16x8 c0, c1, c2, c3, p0, p1, p2, p3;
                if (hc) LOAD_W(R.wbufs[s][1], c0, c1, c2, c3);
                if (hp) LOAD_W(R.wbufs[s ^ 1][0], p0, p1, p2, p3);
                if (hc) ITER_BODY(cst_cur, c0, c1, c2, c3, R.wbufs[s][0]);
                if (hp) ITER_BODY(cst_prv, p0, p1, p2, p3, R.wbufs[s ^ 1][1]);
                __syncthreads();
            }
            // ---------- j=2: iter3(t) || iter8(t-1)
            {
                f16x8 c0, c1, c2, c3, p0, p1, p2, p3;
                if (hc) LOAD_W(R.wbufs[s][0], c0, c1, c2, c3);
                if (hp) LOAD_W(R.wbufs[s ^ 1][1], p0, p1, p2, p3);
                if (hc) ITER_BODY(cst_cur, c0, c1, c2, c3, R.wbufs[s][1]);
                if (hp) ITER_BODY(cst_prv, p0, p1, p2, p3, R.wbufs[s ^ 1][0]);
                __syncthreads();
            }
            // ---------- j=3: iter4(t) || EPILOGUE(t-1)  (waves 0-1)
            {
                f16x8 c0, c1, c2, c3;
                if (hc) LOAD_W(R.wbufs[s][1], c0, c1, c2, c3);
                const bool ep = hp && (wave < 2);
                f16x8 xbp, ybp, w0f, w1f, w2f, w3f;
                if (ep) {
                    xbp = *(const f16x8*)(R.xbuf[s ^ 1] + rd_off);
                    ybp = *(const f16x8*)(R.ybuf[(t - 1) % 3] + rd_off);
                    LOAD_W(R.wbufs[s ^ 1][0], w0f, w1f, w2f, w3f);
                }
                if (hc) ITER_BODY(cst_cur, c0, c1, c2, c3, R.wbufs[s][0]);
                if (ep) {
                    f32x4 ea = MFMA16(EPf[0].v, xbp, zero4);
                    f32x4 eb = MFMA16(EPf[1].v, ybp, zero4);
                    ea = MFMA16(EPf[2].v, w0f, ea); eb = MFMA16(EPf[3].v, w1f, eb);
                    ea = MFMA16(EPf[4].v, w2f, ea); eb = MFMA16(EPf[5].v, w3f, eb);
                    f32x4 ez = ea + eb;
                    const int m = l15, tp = t - 1;
                    if (wave == 0 && q < 2) {
                        // rows 0..7: u -> global
                        const size_t o = ((size_t)(b0r + m) * T + tp) * (2 * OUT + 1);
                        out[o + 4 * q + 0] = ez.x; out[o + 4 * q + 1] = ez.y;
                        out[o + 4 * q + 2] = ez.z; out[o + 4 * q + 3] = ez.w;
                    } else if (wave == 0 || q < 2) {
                        // x_next cols: wave0 q2,q3 -> 0..7 ; wave1 q0,q1 -> 8..15
                        const int cb = (wave == 0) ? (4 * q - 8) : (8 + 4 * q);
                        float4 xv = *(const float4*)&R.xs[m][cb];
                        float4 xn;
                        xn.x = fmaf(DT, ez.x, xv.x); xn.y = fmaf(DT, ez.y, xv.y);
                        xn.z = fmaf(DT, ez.z, xv.z); xn.w = fmaf(DT, ez.w, xv.w);
                        *(float4*)&R.xs[m][cb] = xn;
                        // restage x_t (fp16) into xbuf[s] for u4(t) next round
                        uint2 pk;
                        pk.x = pkrtz_u(xn.x, xn.y); pk.y = pkrtz_u(xn.z, xn.w);
                        *(uint2*)(R.xbuf[s] + ((cb >> 3) * 16 + m) * 16 + (cb & 7) * 2) = pk;
                    }
                }
                __syncthreads();
            }
            // ---------- j=4: u4(t) [exact cst + iter5] + stage y(t+2)
            if (hc) {
                f16x8 xb = *(const f16x8*)(R.xbuf[s] + rd_off);
                f16x8 a0, a1, a2, a3;
                LOAD_W(R.wbufs[s][0], a0, a1, a2, a3);
                f32x4 pc = MFMA16(Cx.v, xb, csty);   // exact cst = cstx + csty
                f32x4 p0 = MFMA16(D[0].v, a0, zero4);
                f32x4 p1 = MFMA16(D[1].v, a1, zero4);
                p0 = MFMA16(D[2].v, a2, p0);
                p1 = MFMA16(D[3].v, a3, p1);
                f32x4 z = pc + p0 + p1;
                uint2 w5p;
                w5p.x = tanh2_pk(z.x, z.y); w5p.y = tanh2_pk(z.z, z.w);
                *(uint2*)(R.wbufs[s][1] + wa) = w5p;
                hx2 = hx1; hx1 = pc - csty;
                cst_cur = pc;
                if (tid < 256) {   // stage y(t+2) into the ring slot freed at j=3
                    int m2 = tid >> 4, pr = tid & 15, k = 2 * pr;
                    int tt = (t + 2 < T) ? (t + 2) : (T - 1);
                    const float* yp = obs + ((size_t)(b0r + m2) * T + tt) * IN + k;
                    *(uint*)(R.ybuf[(t + 2) % 3] + ((k >> 3) * 16 + m2) * 16 + (k & 7) * 2) =
                        pkrtz_u(yp[0], yp[1]);
                }
                __syncthreads();
            }
            cst_prv = cst_cur;
        }
    } else {
        // ================= value branch (fp16 MFMA GEMM) =================
        // out1 = tanh(obs @ W0 + b0); out2 = tanh(out1 @ W1 + b1);
        // value = out2 @ W2 + b2.  Computed transposed: C = W^T(A) * X^T(B),
        // C row = out-col (oc), C col = batch row.  Weights as register
        // A-fragments; inter-layer bounce via wave-private LDS scratch.
        char* scr = sm.v.scr[wave];

        ABu Af0[4], Af1[4][2];
        f32x4 bc0[4], bc1[4];
        float W2v[4][4], lsv[8];
        const float b2v = b2[0];
#pragma unroll
        for (int t2 = 0; t2 < 4; ++t2) {
            const int oc = t2 * 16 + l15;
#pragma unroll
            for (int j = 0; j < 8; ++j) {
                int k = 8 * q + j;
                Af0[t2].h[j]    = (f16)W0[k * 64 + oc];
                Af1[t2][0].h[j] = (f16)W1[k * 64 + oc];
                Af1[t2][1].h[j] = (f16)W1[(32 + k) * 64 + oc];
            }
#pragma unroll
            for (int r = 0; r < 4; ++r) {
                int ocr = t2 * 16 + 4 * q + r;
                bc0[t2][r] = b0[ocr];
                bc1[t2][r] = b1[ocr];
                W2v[t2][r] = W2[ocr];
            }
        }
#pragma unroll
        for (int i = 0; i < 8; ++i) lsv[i] = log_stds[i];

        const size_t rowbase = (size_t)(blockIdx.x - NBLK_R) * 512 + wave * 64;

#pragma unroll
        for (int bt = 0; bt < 4; ++bt) {
            const size_t row = rowbase + bt * 16 + l15;
            // B-frag of obs^T: lane(q,l15) holds feat 8q..8q+7 of batch row l15
            const float* op = obs + row * IN + 8 * q;
            float4 o0 = *(const float4*)op;
            float4 o1 = *(const float4*)(op + 4);
            ABu Bo;
            ((uint*)&Bo.v)[0] = pkrtz_u(o0.x, o0.y);
            ((uint*)&Bo.v)[1] = pkrtz_u(o0.z, o0.w);
            ((uint*)&Bo.v)[2] = pkrtz_u(o1.x, o1.y);
            ((uint*)&Bo.v)[3] = pkrtz_u(o1.z, o1.w);
            // layer0 (K=32) + tanh -> packed h^T into scratch (chunk layout)
#pragma unroll
            for (int t2 = 0; t2 < 4; ++t2) {
                f32x4 a = MFMA16(Af0[t2].v, Bo.v, bc0[t2]);
                uint2 hp;
                hp.x = tanh2_pk(a.x, a.y); hp.y = tanh2_pk(a.z, a.w);
                // k0 = 16*t2 + 4*q: chunk cc = 2*t2 + (q>>1), byte (q&1)*8
                *(uint2*)(scr + ((2 * t2 + (q >> 1)) * 16 + l15) * 16 + (q & 1) * 8) = hp;
            }
            // same-wave DS ops complete in order: no barrier needed
            f16x8 bh0 = *(const f16x8*)(scr + rd_off);
            f16x8 bh1 = *(const f16x8*)(scr + rd_off + 1024);
            // layer1 (K=64) + tanh + W2 dot
            float vpart = 0.f;
#pragma unroll
            for (int t2 = 0; t2 < 4; ++t2) {
                f32x4 a = MFMA16(Af1[t2][0].v, bh0, bc1[t2]);
                a = MFMA16(Af1[t2][1].v, bh1, a);
                vpart = fmaf(fast_tanh(a.x), W2v[t2][0], vpart);
                vpart = fmaf(fast_tanh(a.y), W2v[t2][1], vpart);
                vpart = fmaf(fast_tanh(a.z), W2v[t2][2], vpart);
                vpart = fmaf(fast_tanh(a.w), W2v[t2][3], vpart);
            }
            // reduce over the 4 q-groups (lanes l15, l15+16, l15+32, l15+48)
            vpart += __shfl_xor(vpart, 16);
            vpart += __shfl_xor(vpart, 32);
            const size_t ob = row * (2 * OUT + 1);
            if (q == 0) {
                out[ob + 2 * OUT] = vpart + b2v;
            } else if (q == 1) {
                out[ob + 8]  = lsv[0]; out[ob + 9]  = lsv[1];
                out[ob + 10] = lsv[2]; out[ob + 11] = lsv[3];
            } else if (q == 2) {
                out[ob + 12] = lsv[4]; out[ob + 13] = lsv[5];
                out[ob + 14] = lsv[6]; out[ob + 15] = lsv[7];
            }
        }
    }
}

extern "C" void kernel_launch(void* const* d_in, const int* in_sizes, int n_in,
                              void* d_out, int out_size, void* d_ws, size_t ws_size,
                              hipStream_t stream) {
    const float* obs      = (const float*)d_in[0];
    const float* x0       = (const float*)d_in[1];
    const float* A_T      = (const float*)d_in[2];
    const float* Bw_T     = (const float*)d_in[3];
    const float* By_T     = (const float*)d_in[4];
    const float* Cv_T     = (const float*)d_in[5];
    const float* Dvw_T    = (const float*)d_in[6];
    const float* Dvy_T    = (const float*)d_in[7];
    const float* Cu_T     = (const float*)d_in[8];
    const float* Duw_T    = (const float*)d_in[9];
    const float* Duy_T    = (const float*)d_in[10];
    const float* log_stds = (const float*)d_in[11];
    const float* W0       = (const float*)d_in[12];
    const float* b0       = (const float*)d_in[13];
    const float* W1       = (const float*)d_in[14];
    const float* b1       = (const float*)d_in[15];
    const float* W2       = (const float*)d_in[16];
    const float* b2       = (const float*)d_in[17];
    float* out = (float*)d_out;

    fused_kernel<<<NBLK_R + NBLK_V, NTHR, 0, stream>>>(
        obs, x0, A_T, Bw_T, By_T, Cv_T, Dvw_T, Dvy_T, Cu_T, Duw_T, Duy_T,
        log_stds, W0, b0, W1, b1, W2, b2, out);
}

// Round 4
// 337.745 us; speedup vs baseline: 1.2095x; 1.1695x over previous
//
#include <hip/hip_runtime.h>
#include <cstddef>

#define B 2048
#define T 128
#define S 16
#define NL 128
#define IN 32
#define OUT 8
#define DT 0.01f

// Rinn branch: 7 fixed-point iterations per t (truncation bound: rho<=0.65 ->
// w tail 0.65^6*0.6 ~ 0.045 -> u err ~0.06 < tolerance; measured absmax at 8
// iters was 0.016-0.031).  Two timesteps software-pipelined with a 4-round
// stagger: r0=[ext-cst+i1 || i5-exact], r1=[i2||i6], r2=[i3||i7],
// r3=[i4||epilogue].  Iters 1-4 of t use cstx extrapolated 2 steps ahead,
// cstx(3*x_{t-2}-2*x_{t-3}) (error ~3e-3, contracted x0.27 by the 3 exact
// iters) so i1 is independent of i5 inside r0.  y(t+2) global loads issue at
// r0 into registers and LDS-write at r2 (ring-4), keeping HBM latency out of
// the barrier chain.  Rounds/block: 5*129=645 -> 4*129=516.

#define NBLK_R (B / 16)          // 128 rinn blocks, 16 batch rows each
#define NBLK_V ((B * T) / 512)   // 512 value blocks, 512 samples each
#define NTHR 512

typedef unsigned int uint;
typedef _Float16 f16;
typedef f16 f16x8 __attribute__((ext_vector_type(8)));
typedef __fp16 fp16x2_n __attribute__((ext_vector_type(2)));  // native cvt_pkrtz type
typedef float f32x4 __attribute__((ext_vector_type(4)));

union ABu { f16x8 v; f16 h[8]; };

#define MFMA16(A, Bv, C) __builtin_amdgcn_mfma_f32_16x16x32_f16((A), (Bv), (C), 0, 0, 0)

__device__ __forceinline__ uint pkrtz_u(float a, float b) {
    fp16x2_n p = __builtin_amdgcn_cvt_pkrtz(a, b);
    return __builtin_bit_cast(uint, p);
}

// value branch tanh (has slack, keep safe clamp)
__device__ __forceinline__ float fast_tanh(float x) {
    float e = __expf(fminf(x, 10.f) * 2.f);
    return fmaf(-2.f, __builtin_amdgcn_rcpf(e + 1.f), 1.f);
}

// paired tanh -> packed half2, one shared v_rcp
__device__ __forceinline__ uint tanh2_pk(float a, float b) {
    float ea = __expf(a * 2.f);
    float eb = __expf(b * 2.f);
    float da = ea + 1.f, db = eb + 1.f;
    float r  = __builtin_amdgcn_rcpf(da * db);
    float ta = fmaf(-2.f, db * r, 1.f);
    float tb = fmaf(-2.f, da * r, 1.f);
    return pkrtz_u(ta, tb);
}

// LDS chunk layout for a 16(m) x K(k) fp16 matrix: chunk (cc=k>>3, m) holds 8
// consecutive k of row m at byte ((cc*16+m)*16 + (k&7)*2).  B-fragment read for
// MFMA k-step s (quad q, lane m=l15): one ds_read_b128 at ((s*4+q)*16+m)*16.

struct __align__(16) RinnS {
    char wbufs[2][2][4096];  // per-slot (t&1) w ping-pong buffers (16 x 128 fp16)
    char xbuf[2][1024];      // x_t (f16, K=32 with k>=16 zero pad), per t parity
    char ybuf[4][1024];      // y_t (f16, K=32), ring of 4
    float xs[16][16];        // fp32 master copy of state
};
struct __align__(16) ValueS {
    char scr[8][2048];       // per-wave h^T bounce scratch (64k x 16m fp16)
};
union SmU { RinnS r; ValueS v; };

#define LOAD_W(rb, A0, A1, A2, A3) do { const char* _p = (rb);                 \
    A0 = *(const f16x8*)(_p + rd_off);        A1 = *(const f16x8*)(_p + rd_off + 1024); \
    A2 = *(const f16x8*)(_p + rd_off + 2048); A3 = *(const f16x8*)(_p + rd_off + 3072); } while (0)

#define ITER_BODY(CST, A0, A1, A2, A3, WDST) do {                              \
    f32x4 _p0 = (CST), _p1 = {0.f, 0.f, 0.f, 0.f};                             \
    _p0 = MFMA16(D[0].v, A0, _p0); _p1 = MFMA16(D[1].v, A1, _p1);              \
    _p0 = MFMA16(D[2].v, A2, _p0); _p1 = MFMA16(D[3].v, A3, _p1);              \
    f32x4 _z = _p0 + _p1;                                                      \
    uint2 _w; _w.x = tanh2_pk(_z.x, _z.y); _w.y = tanh2_pk(_z.z, _z.w);        \
    *(uint2*)((WDST) + wa) = _w; } while (0)

__global__ void __launch_bounds__(NTHR, 1)
fused_kernel(const float* __restrict__ obs, const float* __restrict__ x0,
             const float* __restrict__ A_T, const float* __restrict__ Bw_T,
             const float* __restrict__ By_T, const float* __restrict__ Cv_T,
             const float* __restrict__ Dvw_T, const float* __restrict__ Dvy_T,
             const float* __restrict__ Cu_T, const float* __restrict__ Duw_T,
             const float* __restrict__ Duy_T, const float* __restrict__ log_stds,
             const float* __restrict__ W0, const float* __restrict__ b0,
             const float* __restrict__ W1, const float* __restrict__ b1,
             const float* __restrict__ W2, const float* __restrict__ b2,
             float* __restrict__ out) {
    __shared__ SmU sm;
    const int tid = threadIdx.x;
    const int wave = tid >> 6, lane = tid & 63;
    const int q = lane >> 4, l15 = lane & 15;
    const int rd_off = (q * 16 + l15) * 16;  // + s*1024

    if (blockIdx.x < NBLK_R) {
        // ======================= recurrent branch =======================
        RinnS& R = sm.r;
        const int b0r = blockIdx.x * 16;
        const int ct = wave * 16;   // this wave's single 16-col tile of NL

        // ---- iteration-invariant A-operand fragments (fp16) ----
        // Z^T = Dvw^T (A) * w^T (B);  A[c_local][k]: c=ct+l15, k=32s+8q+j
        ABu D[4];
#pragma unroll
        for (int s2 = 0; s2 < 4; ++s2)
#pragma unroll
            for (int j = 0; j < 8; ++j) {
                int k = 32 * s2 + 8 * q + j;
                D[s2].h[j] = (f16)Dvw_T[k * NL + ct + l15];
            }
        // cstx^T = Cv^T (A, K=32 padded) * x^T ; csty^T = Dvy^T (A, K=32) * y^T
        ABu Cx, Cy;
#pragma unroll
        for (int j = 0; j < 8; ++j) {
            int k = 8 * q + j;
            Cx.h[j] = (f16)((k < 16) ? Cv_T[k * NL + ct + l15] : 0.f);
            Cy.h[j] = (f16)Dvy_T[k * NL + ct + l15];
        }
        // epilogue: [u|xn]^T = W^T (A) * [x(32)|y(32)|w(128)]^T (B), K=192
        ABu EPf[6];
        if (wave < 2) {
            int oc = wave * 16 + l15;  // 0..7=u, 8..23=xnext, >=24 pad
#pragma unroll
            for (int s2 = 0; s2 < 6; ++s2)
#pragma unroll
                for (int j = 0; j < 8; ++j) {
                    int k = 32 * s2 + 8 * q + j;
                    float v = 0.f;
                    if (oc < 24) {
                        if (k < 16)       v = (oc < 8) ? Cu_T[k * OUT + oc] : A_T[k * S + (oc - 8)];
                        else if (k >= 32 && k < 64) { int ky = k - 32;
                                          v = (oc < 8) ? Duy_T[ky * OUT + oc] : By_T[ky * S + (oc - 8)]; }
                        else if (k >= 64) { int kw = k - 64;
                                          v = (oc < 8) ? Duw_T[kw * OUT + oc] : Bw_T[kw * S + (oc - 8)]; }
                    }
                    EPf[s2].h[j] = (f16)v;
                }
        }

        // ---- init staging: xs, xbuf[0]=xbuf[1]=x0 (+zero pads), ybuf[0/1]=y0/y1
        if (tid < 256) { int m = tid >> 4, c = tid & 15; R.xs[m][c] = x0[(b0r + m) * S + c]; }
        if (tid < 128) {
            int m = tid >> 3, pr = tid & 7, k = 2 * pr;
            uint u = pkrtz_u(x0[(b0r + m) * S + k], x0[(b0r + m) * S + k + 1]);
            uint off = ((k >> 3) * 16 + m) * 16 + (k & 7) * 2;
            *(uint*)(R.xbuf[0] + off) = u;
            *(uint*)(R.xbuf[1] + off) = u;
        } else if (tid < 384) {   // zero pads: bytes 512..1023 of both xbufs
            int i = tid - 128, buf = i >> 7, d = i & 127;
            *(uint*)(R.xbuf[buf] + 512 + d * 4) = 0u;
        }
        {   // ybuf[0] <- y(0), ybuf[1] <- y(1): 512 pair-slots, one per thread
            int buf = tid >> 8, ii = tid & 255, m = ii >> 4, pr = ii & 15, k = 2 * pr;
            const float* yp = obs + ((size_t)(b0r + m) * T + buf) * IN + k;
            *(uint*)(R.ybuf[buf] + ((k >> 3) * 16 + m) * 16 + (k & 7) * 2) =
                pkrtz_u(yp[0], yp[1]);
        }

        const int wa = (((ct >> 3) + (q >> 1)) * 16 + l15) * 16 + (q & 1) * 8;
        __syncthreads();

        f32x4 cst_cur = {0.f, 0.f, 0.f, 0.f}, cst_prv = {0.f, 0.f, 0.f, 0.f};
        f32x4 csty_cur = {0.f, 0.f, 0.f, 0.f}, csty_prv = {0.f, 0.f, 0.f, 0.f};
        f32x4 hx1 = {0.f, 0.f, 0.f, 0.f}, hx2 = {0.f, 0.f, 0.f, 0.f};
        const f32x4 zero4 = {0.f, 0.f, 0.f, 0.f};

        for (int t = 0; t <= T; ++t) {
            const int s = t & 1;
            const bool hc = (t < T);   // current chain (t): i1..i4
            const bool hp = (t > 0);   // previous chain (t-1): i5..i7 + ep
            float ys0 = 0.f, ys1 = 0.f;
            int ywoff = 0;

            // ---------- r0: ext-cst + i1 (t) || i5 exact-cst (t-1); y-loads issue
            {
                if (hc && tid < 256) {   // y(t+2) load issue -> regs (write at r2)
                    int m2 = tid >> 4, pr = tid & 15, k = 2 * pr;
                    int tt = (t + 2 < T) ? (t + 2) : (T - 1);
                    const float* yp = obs + ((size_t)(b0r + m2) * T + tt) * IN + k;
                    ys0 = yp[0]; ys1 = yp[1];
                    ywoff = ((k >> 3) * 16 + m2) * 16 + (k & 7) * 2;
                }
                f16x8 yb, xbp, a0, a1, a2, a3;
                if (hc) yb = *(const f16x8*)(R.ybuf[t & 3] + rd_off);
                if (hp) {
                    xbp = *(const f16x8*)(R.xbuf[s ^ 1] + rd_off);
                    LOAD_W(R.wbufs[s ^ 1][0], a0, a1, a2, a3);   // i4 output
                }
                if (hc) {
                    csty_cur = MFMA16(Cy.v, yb, zero4);
                    f32x4 ext;
                    if (t == 0) {
                        f16x8 xb0 = *(const f16x8*)(R.xbuf[1] + rd_off);
                        f32x4 cx = MFMA16(Cx.v, xb0, zero4);
                        hx1 = cx; hx2 = cx;
                        ext = cx;
                    } else {
                        // 2-step-ahead linear extrapolation from x_{t-2}, x_{t-3}
                        ext = 3.f * hx1 - 2.f * hx2;
                    }
                    cst_cur = ext + csty_cur;
                    uint2 w0p;
                    w0p.x = tanh2_pk(cst_cur.x, cst_cur.y);
                    w0p.y = tanh2_pk(cst_cur.z, cst_cur.w);
                    *(uint2*)(R.wbufs[s][1] + wa) = w0p;         // i1 -> [s][1]
                }
                if (hp) {
                    f32x4 pc = MFMA16(Cx.v, xbp, csty_prv);      // exact cst(t-1)
                    ITER_BODY(pc, a0, a1, a2, a3, R.wbufs[s ^ 1][1]);  // i5
                    hx2 = hx1; hx1 = pc - csty_prv;              // cstx(x_{t-1})
                    cst_prv = pc;                                // i6,i7 use exact
                }
                __syncthreads();
            }
            // ---------- r1: i2(t) || i6(t-1)
            {
                f16x8 c0, c1, c2, c3, p0, p1, p2, p3;
                if (hc) LOAD_W(R.wbufs[s][1], c0, c1, c2, c3);       // i1 out
                if (hp) LOAD_W(R.wbufs[s ^ 1][1], p0, p1, p2, p3);   // i5 out
                if (hc) ITER_BODY(cst_cur, c0, c1, c2, c3, R.wbufs[s][0]);
                if (hp) ITER_BODY(cst_prv, p0, p1, p2, p3, R.wbufs[s ^ 1][0]);
                __syncthreads();
            }
            // ---------- r2: i3(t) || i7(t-1); y-stage LDS write
            {
                f16x8 c0, c1, c2, c3, p0, p1, p2, p3;
                if (hc) LOAD_W(R.wbufs[s][0], c0, c1, c2, c3);       // i2 out
                if (hp) LOAD_W(R.wbufs[s ^ 1][0], p0, p1, p2, p3);   // i6 out
                if (hc) ITER_BODY(cst_cur, c0, c1, c2, c3, R.wbufs[s][1]);
                if (hp) ITER_BODY(cst_prv, p0, p1, p2, p3, R.wbufs[s ^ 1][1]);
                if (hc && tid < 256)
                    *(uint*)(R.ybuf[(t + 2) & 3] + ywoff) = pkrtz_u(ys0, ys1);
                __syncthreads();
            }
            // ---------- r3: i4(t) || EPILOGUE(t-1)  (waves 0-1)
            {
                f16x8 c0, c1, c2, c3;
                if (hc) LOAD_W(R.wbufs[s][1], c0, c1, c2, c3);       // i3 out
                const bool ep = hp && (wave < 2);
                f16x8 xbp, ybp, w0f, w1f, w2f, w3f;
                if (ep) {
                    xbp = *(const f16x8*)(R.xbuf[s ^ 1] + rd_off);
                    ybp = *(const f16x8*)(R.ybuf[(t - 1) & 3] + rd_off);
                    LOAD_W(R.wbufs[s ^ 1][1], w0f, w1f, w2f, w3f);   // i7 out
                }
                if (hc) ITER_BODY(cst_cur, c0, c1, c2, c3, R.wbufs[s][0]);  // i4
                if (ep) {
                    f32x4 ea = MFMA16(EPf[0].v, xbp, zero4);
                    f32x4 eb = MFMA16(EPf[1].v, ybp, zero4);
                    ea = MFMA16(EPf[2].v, w0f, ea); eb = MFMA16(EPf[3].v, w1f, eb);
                    ea = MFMA16(EPf[4].v, w2f, ea); eb = MFMA16(EPf[5].v, w3f, eb);
                    f32x4 ez = ea + eb;
                    const int m = l15, tp = t - 1;
                    if (wave == 0 && q < 2) {
                        // rows 0..7: u -> global
                        const size_t o = ((size_t)(b0r + m) * T + tp) * (2 * OUT + 1);
                        out[o + 4 * q + 0] = ez.x; out[o + 4 * q + 1] = ez.y;
                        out[o + 4 * q + 2] = ez.z; out[o + 4 * q + 3] = ez.w;
                    } else if (wave == 0 || q < 2) {
                        // x_next cols: wave0 q2,q3 -> 0..7 ; wave1 q0,q1 -> 8..15
                        const int cb = (wave == 0) ? (4 * q - 8) : (8 + 4 * q);
                        float4 xv = *(const float4*)&R.xs[m][cb];
                        float4 xn;
                        xn.x = fmaf(DT, ez.x, xv.x); xn.y = fmaf(DT, ez.y, xv.y);
                        xn.z = fmaf(DT, ez.z, xv.z); xn.w = fmaf(DT, ez.w, xv.w);
                        *(float4*)&R.xs[m][cb] = xn;
                        // restage x_t (fp16) into xbuf[s] for i5(t) next r0
                        uint2 pk;
                        pk.x = pkrtz_u(xn.x, xn.y); pk.y = pkrtz_u(xn.z, xn.w);
                        *(uint2*)(R.xbuf[s] + ((cb >> 3) * 16 + m) * 16 + (cb & 7) * 2) = pk;
                    }
                }
                __syncthreads();
            }
            csty_prv = csty_cur;
        }
    } else {
        // ================= value branch (fp16 MFMA GEMM) =================
        // out1 = tanh(obs @ W0 + b0); out2 = tanh(out1 @ W1 + b1);
        // value = out2 @ W2 + b2.  Computed transposed: C = W^T(A) * X^T(B).
        // Weights as register A-fragments; inter-layer bounce via wave-private
        // LDS scratch (same-wave DS ordering, no barriers).
        char* scr = sm.v.scr[wave];

        ABu Af0[4], Af1[4][2];
        f32x4 bc0[4], bc1[4];
        float W2v[4][4], lsv[8];
        const float b2v = b2[0];
#pragma unroll
        for (int t2 = 0; t2 < 4; ++t2) {
            const int oc = t2 * 16 + l15;
#pragma unroll
            for (int j = 0; j < 8; ++j) {
                int k = 8 * q + j;
                Af0[t2].h[j]    = (f16)W0[k * 64 + oc];
                Af1[t2][0].h[j] = (f16)W1[k * 64 + oc];
                Af1[t2][1].h[j] = (f16)W1[(32 + k) * 64 + oc];
            }
#pragma unroll
            for (int r = 0; r < 4; ++r) {
                int ocr = t2 * 16 + 4 * q + r;
                bc0[t2][r] = b0[ocr];
                bc1[t2][r] = b1[ocr];
                W2v[t2][r] = W2[ocr];
            }
        }
#pragma unroll
        for (int i = 0; i < 8; ++i) lsv[i] = log_stds[i];

        const size_t rowbase = (size_t)(blockIdx.x - NBLK_R) * 512 + wave * 64;

#pragma unroll
        for (int bt = 0; bt < 4; ++bt) {
            const size_t row = rowbase + bt * 16 + l15;
            // B-frag of obs^T: lane(q,l15) holds feat 8q..8q+7 of batch row l15
            const float* op = obs + row * IN + 8 * q;
            float4 o0 = *(const float4*)op;
            float4 o1 = *(const float4*)(op + 4);
            ABu Bo;
            ((uint*)&Bo.v)[0] = pkrtz_u(o0.x, o0.y);
            ((uint*)&Bo.v)[1] = pkrtz_u(o0.z, o0.w);
            ((uint*)&Bo.v)[2] = pkrtz_u(o1.x, o1.y);
            ((uint*)&Bo.v)[3] = pkrtz_u(o1.z, o1.w);
            // layer0 (K=32) + tanh -> packed h^T into scratch (chunk layout)
#pragma unroll
            for (int t2 = 0; t2 < 4; ++t2) {
                f32x4 a = MFMA16(Af0[t2].v, Bo.v, bc0[t2]);
                uint2 hp;
                hp.x = tanh2_pk(a.x, a.y); hp.y = tanh2_pk(a.z, a.w);
                // k0 = 16*t2 + 4*q: chunk cc = 2*t2 + (q>>1), byte (q&1)*8
                *(uint2*)(scr + ((2 * t2 + (q >> 1)) * 16 + l15) * 16 + (q & 1) * 8) = hp;
            }
            // same-wave DS ops complete in order: no barrier needed
            f16x8 bh0 = *(const f16x8*)(scr + rd_off);
            f16x8 bh1 = *(const f16x8*)(scr + rd_off + 1024);
            // layer1 (K=64) + tanh + W2 dot
            float vpart = 0.f;
#pragma unroll
            for (int t2 = 0; t2 < 4; ++t2) {
                f32x4 a = MFMA16(Af1[t2][0].v, bh0, bc1[t2]);
                a = MFMA16(Af1[t2][1].v, bh1, a);
                vpart = fmaf(fast_tanh(a.x), W2v[t2][0], vpart);
                vpart = fmaf(fast_tanh(a.y), W2v[t2][1], vpart);
                vpart = fmaf(fast_tanh(a.z), W2v[t2][2], vpart);
                vpart = fmaf(fast_tanh(a.w), W2v[t2][3], vpart);
            }
            // reduce over the 4 q-groups (lanes l15, l15+16, l15+32, l15+48)
            vpart += __shfl_xor(vpart, 16);
            vpart += __shfl_xor(vpart, 32);
            const size_t ob = row * (2 * OUT + 1);
            if (q == 0) {
                out[ob + 2 * OUT] = vpart + b2v;
            } else if (q == 1) {
                out[ob + 8]  = lsv[0]; out[ob + 9]  = lsv[1];
                out[ob + 10] = lsv[2]; out[ob + 11] = lsv[3];
            } else if (q == 2) {
                out[ob + 12] = lsv[4]; out[ob + 13] = lsv[5];
                out[ob + 14] = lsv[6]; out[ob + 15] = lsv[7];
            }
        }
    }
}

extern "C" void kernel_launch(void* const* d_in, const int* in_sizes, int n_in,
                              void* d_out, int out_size, void* d_ws, size_t ws_size,
                              hipStream_t stream) {
    const float* obs      = (const float*)d_in[0];
    const float* x0       = (const float*)d_in[1];
    const float* A_T      = (const float*)d_in[2];
    const float* Bw_T     = (const float*)d_in[3];
    const float* By_T     = (const float*)d_in[4];
    const float* Cv_T     = (const float*)d_in[5];
    const float* Dvw_T    = (const float*)d_in[6];
    const float* Dvy_T    = (const float*)d_in[7];
    const float* Cu_T     = (const float*)d_in[8];
    const float* Duw_T    = (const float*)d_in[9];
    const float* Duy_T    = (const float*)d_in[10];
    const float* log_stds = (const float*)d_in[11];
    const float* W0       = (const float*)d_in[12];
    const float* b0       = (const float*)d_in[13];
    const float* W1       = (const float*)d_in[14];
    const float* b1       = (const float*)d_in[15];
    const float* W2       = (const float*)d_in[16];
    const float* b2       = (const float*)d_in[17];
    float* out = (float*)d_out;

    fused_kernel<<<NBLK_R + NBLK_V, NTHR, 0, stream>>>(
        obs, x0, A_T, Bw_T, By_T, Cv_T, Dvw_T, Dvy_T, Cu_T, Duw_T, Duy_T,
        log_stds, W0, b0, W1, b1, W2, b2, out);
}